// Round 10
// baseline (483.406 us; speedup 1.0000x reference)
//
#include <hip/hip_runtime.h>
#include <hip/hip_fp16.h>

constexpr int N_NODES = 100000;
constexpr int N_EDGES = 3200000;
constexpr int NB2 = (N_NODES + 63) >> 6;     // 1563 lists, 64 dst-nodes each
constexpr int LCAP = 2432;                   // mean 2048, sd ~45 -> +8.5 sigma
constexpr int TILE = 8192;
constexpr int NTILES = (N_EDGES + TILE - 1) / TILE;  // 391
constexpr int NWIN = 8;                      // src>>14 windows (0..6 used; 7 = guard)
constexpr int NKEY = NWIN * 64;              // 512 sort keys (window-major, row-minor)

// ---------------------------------------------------------------------------
// K0: x (fp32) -> xh (fp16). ~77 MB streamed. fp16 rel err 2^-12; round-8
// measured: absmax unchanged vs fp32 path.
// ---------------------------------------------------------------------------
__global__ __launch_bounds__(256) void cvt_kernel(const float* __restrict__ x,
                                                  __half* __restrict__ xh) {
  const int stride = gridDim.x * 256;
  const int total = N_NODES * 128 / 4;
  for (int i = blockIdx.x * 256 + threadIdx.x; i < total; i += stride) {
    float4 v = ((const float4*)x)[i];
    ((__half2*)xh)[2 * i] = __floats2half2_rn(v.x, v.y);
    ((__half2*)xh)[2 * i + 1] = __floats2half2_rn(v.z, v.w);
  }
}

// ---------------------------------------------------------------------------
// K1 (bin v4): 2-pass per-tile counting sort into per-list contiguous global
// ranges (ONE atomicAdd claim per (tile,list)). Round-8 inference: bin was
// issue/latency-bound at 1.5 blocks/CU (6 waves/CU). Same TILE=8192 (keeps
// ~5.2-record runs -> ~2.5x write amp), 1024 threads -> 4x waves/CU.
// Record = int2{ src | (dst&63)<<17 , w_bits }.
// ---------------------------------------------------------------------------
__global__ __launch_bounds__(1024) void bin4_kernel(
    const int* __restrict__ src, const int* __restrict__ dst,
    const float* __restrict__ w, int* __restrict__ gtail,
    int2* __restrict__ lists) {
  __shared__ int lcnt[NB2];    // hist, then intra-tile cursor
  __shared__ int lbase[NB2];   // claimed global base
  const int t = threadIdx.x;
  const int e0 = blockIdx.x * TILE;
  const int n = min(TILE, N_EDGES - e0);

  for (int i = t; i < NB2; i += 1024) lcnt[i] = 0;
  __syncthreads();

  for (int off = t; off < n; off += 1024)
    atomicAdd(&lcnt[(dst[e0 + off] >> 6)], 1);   // dst<100000 -> l<=1562
  __syncthreads();

  for (int i = t; i < NB2; i += 1024) {
    int c = lcnt[i];
    lbase[i] = (c > 0) ? atomicAdd(&gtail[i], c) : 0;
    lcnt[i] = 0;
  }
  __syncthreads();

  for (int off = t; off < n; off += 1024) {
    int e = e0 + off;
    int d = dst[e];
    int l = d >> 6;
    int p = lbase[l] + atomicAdd(&lcnt[l], 1);
    if ((unsigned)p < (unsigned)LCAP)
      lists[(size_t)l * LCAP + p] =
          make_int2(src[e] | ((d & 63) << 17), __float_as_int(w[e]));
  }
}

// ---------------------------------------------------------------------------
// K2 (agg v5): one block per 64-dst bucket. LDS counting-sort by
// key = (src>>14)*64 + dst-row (512 keys; int atomics only - no fp atomics),
// then 4 waves x 16 rows sweep the 7 src-windows IN THE SAME ORDER across
// all blocks. All 1563 blocks are co-resident (26KB LDS -> 6/CU), start
// together, and have equal per-window work (+-8%) -> statistically aligned
// window sweep -> each XCD's L2 holds the live 4MB x-window. (Round-2/4
// attempts failed because co-residency didn't hold.)
// Predict FETCH 354 -> ~250 MB, dur 120 -> 80-95 us.
// ---------------------------------------------------------------------------
__global__ __launch_bounds__(256) void agg5_kernel(
    const __half* __restrict__ xh, const int2* __restrict__ lists,
    const int* __restrict__ gtail, float* __restrict__ agg_out,
    float* __restrict__ sw) {
  __shared__ int2 sorted[LCAP];          // 19456 B
  __shared__ int kcnt[NKEY];             // 2 KB
  __shared__ int koff[NKEY + 1];
  __shared__ int kcur[NKEY];
  const int b = blockIdx.x;
  const int t = threadIdx.x;
  const int c = min(gtail[b], LCAP);
  const int2* base = lists + (size_t)b * LCAP;

  for (int i = t; i < NKEY; i += 256) kcnt[i] = 0;
  __syncthreads();

  // phase 1: histogram keys (masked: win<=7, row<=63 -> key<512)
  for (int j = t; j < c; j += 256) {
    int rx = base[j].x;
    int key = ((rx & 0x1FFFF) >> 14) * 64 + ((rx >> 17) & 63);
    atomicAdd(&kcnt[key], 1);
  }
  __syncthreads();

  // wave-0 scan of 512 keys: 8 keys per lane, local prefix + shfl scan
  if (t < 64) {
    int base8 = t * 8;
    int loc[8], run = 0;
    #pragma unroll
    for (int i = 0; i < 8; ++i) { loc[i] = run; run += kcnt[base8 + i]; }
    int inc = run;
    #pragma unroll
    for (int d = 1; d < 64; d <<= 1) {
      int u = __shfl_up(inc, d, 64);
      if (t >= d) inc += u;
    }
    int excl = inc - run;
    #pragma unroll
    for (int i = 0; i < 8; ++i) {
      koff[base8 + i] = excl + loc[i];
      kcur[base8 + i] = excl + loc[i];
    }
    if (t == 63) koff[NKEY] = inc;
  }
  __syncthreads();

  // phase 2: counting-sort scatter into LDS (guarded)
  for (int j = t; j < c; j += 256) {
    int2 r = base[j];
    int key = ((r.x & 0x1FFFF) >> 14) * 64 + ((r.x >> 17) & 63);
    int p = atomicAdd(&kcur[key], 1);
    if ((unsigned)p < (unsigned)LCAP) sorted[p] = r;
  }
  __syncthreads();

  // phase 3: window-major sweep; 16 rows/wave, register accumulators
  const int wv = t >> 6, lane = t & 63;
  const int nd = min(64, N_NODES - b * 64);
  const __half2* xh2 = (const __half2*)xh;
  float2 acc[16];
  float sws[16];
  #pragma unroll
  for (int i = 0; i < 16; ++i) { acc[i] = make_float2(0.f, 0.f); sws[i] = 0.f; }

  for (int s = 0; s < NWIN; ++s) {
    #pragma unroll
    for (int ri = 0; ri < 16; ++ri) {
      int key = s * 64 + wv * 16 + ri;
      int j0 = min(koff[key], c), j1 = min(koff[key + 1], c);
      int j = j0;
      for (; j + 4 <= j1; j += 4) {
        int2 e0 = sorted[j];
        int2 e1 = sorted[j + 1];
        int2 e2 = sorted[j + 2];
        int2 e3 = sorted[j + 3];
        float2 v0 = __half22float2(xh2[(size_t)(e0.x & 0x1FFFF) * 64 + lane]);
        float2 v1 = __half22float2(xh2[(size_t)(e1.x & 0x1FFFF) * 64 + lane]);
        float2 v2 = __half22float2(xh2[(size_t)(e2.x & 0x1FFFF) * 64 + lane]);
        float2 v3 = __half22float2(xh2[(size_t)(e3.x & 0x1FFFF) * 64 + lane]);
        float w0 = __int_as_float(e0.y), w1 = __int_as_float(e1.y);
        float w2 = __int_as_float(e2.y), w3 = __int_as_float(e3.y);
        acc[ri].x = fmaf(w0, v0.x, acc[ri].x); acc[ri].y = fmaf(w0, v0.y, acc[ri].y);
        acc[ri].x = fmaf(w1, v1.x, acc[ri].x); acc[ri].y = fmaf(w1, v1.y, acc[ri].y);
        acc[ri].x = fmaf(w2, v2.x, acc[ri].x); acc[ri].y = fmaf(w2, v2.y, acc[ri].y);
        acc[ri].x = fmaf(w3, v3.x, acc[ri].x); acc[ri].y = fmaf(w3, v3.y, acc[ri].y);
        sws[ri] += (w0 + w1) + (w2 + w3);
      }
      for (; j < j1; ++j) {
        int2 e0 = sorted[j];
        float2 v0 = __half22float2(xh2[(size_t)(e0.x & 0x1FFFF) * 64 + lane]);
        float w0 = __int_as_float(e0.y);
        acc[ri].x = fmaf(w0, v0.x, acc[ri].x);
        acc[ri].y = fmaf(w0, v0.y, acc[ri].y);
        sws[ri] += w0;
      }
    }
  }

  #pragma unroll
  for (int ri = 0; ri < 16; ++ri) {
    int r = wv * 16 + ri;
    if (r < nd) {
      ((float2*)agg_out)[(size_t)(b * 64 + r) * 64 + lane] = acc[ri];
      if (lane == 0) sw[b * 64 + r] = sws[ri];
    }
  }
}

// ---------------------------------------------------------------------------
// K3 (linear v3, unchanged): in-place io[r] = io[r]@W^T + sw[r]*b, 64-row
// tiles, Wt-only LDS (2 blocks/CU), broadcast row loads. In-place safe:
// each row read AND written only by the same 16 lanes of one wave.
// ---------------------------------------------------------------------------
__global__ __launch_bounds__(256, 2) void linear3_kernel(
    float* __restrict__ io, const float* __restrict__ W,
    const float* __restrict__ bias, const float* __restrict__ sw) {
  __shared__ float Wt[128][132];   // Wt[k][c] = W[c][k]
  const int t = threadIdx.x;
  const int row0 = blockIdx.x * 64;

  #pragma unroll
  for (int i = 0; i < 16; ++i) {
    int f4 = t + 256 * i;
    int c = f4 >> 5;
    int k = (f4 & 31) * 4;
    float4 v = *(const float4*)(W + (size_t)c * 128 + k);
    Wt[k + 0][c] = v.x;
    Wt[k + 1][c] = v.y;
    Wt[k + 2][c] = v.z;
    Wt[k + 3][c] = v.w;
  }
  __syncthreads();

  const int tx = t & 15;
  const int ty = t >> 4;
  const float* xr[4];
  #pragma unroll
  for (int i = 0; i < 4; ++i) {
    int r = row0 + ty * 4 + i;
    xr[i] = (r < N_NODES) ? (io + (size_t)r * 128) : io;
  }

  float acc[4][8];
  #pragma unroll
  for (int i = 0; i < 4; ++i)
    #pragma unroll
    for (int j = 0; j < 8; ++j) acc[i][j] = 0.f;

  for (int k0 = 0; k0 < 128; k0 += 4) {
    float4 a[4];
    #pragma unroll
    for (int i = 0; i < 4; ++i) a[i] = *(const float4*)(xr[i] + k0);
    #pragma unroll
    for (int kk = 0; kk < 4; ++kk) {
      int k = k0 + kk;
      float4 b0 = *(const float4*)&Wt[k][tx * 8];
      float4 b1 = *(const float4*)&Wt[k][tx * 8 + 4];
      #pragma unroll
      for (int i = 0; i < 4; ++i) {
        float av = (kk == 0) ? a[i].x : (kk == 1) ? a[i].y
                  : (kk == 2) ? a[i].z : a[i].w;
        acc[i][0] = fmaf(av, b0.x, acc[i][0]);
        acc[i][1] = fmaf(av, b0.y, acc[i][1]);
        acc[i][2] = fmaf(av, b0.z, acc[i][2]);
        acc[i][3] = fmaf(av, b0.w, acc[i][3]);
        acc[i][4] = fmaf(av, b1.x, acc[i][4]);
        acc[i][5] = fmaf(av, b1.y, acc[i][5]);
        acc[i][6] = fmaf(av, b1.z, acc[i][6]);
        acc[i][7] = fmaf(av, b1.w, acc[i][7]);
      }
    }
  }

  float4 bb0 = *(const float4*)(bias + tx * 8);
  float4 bb1 = *(const float4*)(bias + tx * 8 + 4);
  #pragma unroll
  for (int i = 0; i < 4; ++i) {
    int r = row0 + ty * 4 + i;
    if (r < N_NODES) {
      float s = sw[r];
      float4 o0 = make_float4(acc[i][0] + s * bb0.x, acc[i][1] + s * bb0.y,
                              acc[i][2] + s * bb0.z, acc[i][3] + s * bb0.w);
      float4 o1 = make_float4(acc[i][4] + s * bb1.x, acc[i][5] + s * bb1.y,
                              acc[i][6] + s * bb1.z, acc[i][7] + s * bb1.w);
      float* orow = io + (size_t)r * 128 + tx * 8;
      *(float4*)orow = o0;
      *(float4*)(orow + 4) = o1;
    }
  }
}

// ---------------------------------------------------------------------------
extern "C" void kernel_launch(void* const* d_in, const int* in_sizes, int n_in,
                              void* d_out, int out_size, void* d_ws, size_t ws_size,
                              hipStream_t stream) {
  const float* x = (const float*)d_in[0];
  const float* w = (const float*)d_in[1];
  const float* W = (const float*)d_in[2];
  const float* bias = (const float*)d_in[3];
  const int* src = (const int*)d_in[4];
  const int* dst = (const int*)d_in[5];
  float* out = (float*)d_out;

  // workspace: xh 25.6MB | lists 30.4MB | gtail 6.3KB | sw 400KB (~56.5MB)
  char* p = (char*)d_ws;
  __half* xh = (__half*)p;
  size_t o = (size_t)N_NODES * 128 * sizeof(__half);
  o = (o + 255) & ~(size_t)255;
  int2* lists = (int2*)(p + o);
  o += (size_t)NB2 * LCAP * sizeof(int2);
  int* gtail = (int*)(p + o);
  o += (size_t)NB2 * sizeof(int);
  o = (o + 255) & ~(size_t)255;
  float* sw = (float*)(p + o);

  hipMemsetAsync(gtail, 0, (size_t)NB2 * sizeof(int), stream);
  cvt_kernel<<<2048, 256, 0, stream>>>(x, xh);
  bin4_kernel<<<NTILES, 1024, 0, stream>>>(src, dst, w, gtail, lists);
  agg5_kernel<<<NB2, 256, 0, stream>>>(xh, lists, gtail, out, sw);
  linear3_kernel<<<NB2, 256, 0, stream>>>(out, W, bias, sw);
}

// Round 11
// 390.916 us; speedup vs baseline: 1.2366x; 1.2366x over previous
//
#include <hip/hip_runtime.h>
#include <hip/hip_fp16.h>

constexpr int N_NODES = 100000;
constexpr int N_EDGES = 3200000;
constexpr int NB2 = (N_NODES + 63) >> 6;     // 1563 lists, 64 dst-nodes each
constexpr int LCAP = 2432;                   // mean 2048, sd ~45 -> +8.5 sigma
constexpr int TILE2 = 12500;                 // 3.2M / 256 exactly
constexpr int NTILE2 = N_EDGES / TILE2;      // 256 blocks = 1/CU
constexpr int NWIN = 8;                      // src>>14 windows (0..6 used)
constexpr int NKEY = 64 * NWIN;              // 512 keys: ROW-major, window-minor

// ---------------------------------------------------------------------------
// K0: x (fp32) -> xh (fp16). ~77 MB streamed; absmax unchanged (round-8).
// ---------------------------------------------------------------------------
__global__ __launch_bounds__(256) void cvt_kernel(const float* __restrict__ x,
                                                  __half* __restrict__ xh) {
  const int stride = gridDim.x * 256;
  const int total = N_NODES * 128 / 4;
  for (int i = blockIdx.x * 256 + threadIdx.x; i < total; i += stride) {
    float4 v = ((const float4*)x)[i];
    ((__half2*)xh)[2 * i] = __floats2half2_rn(v.x, v.y);
    ((__half2*)xh)[2 * i + 1] = __floats2half2_rn(v.z, v.w);
  }
}

// ---------------------------------------------------------------------------
// K1 (bin v5): full in-LDS counting sort per 12500-edge slice, then
// COALESCED copy-out. Rounds 4-10 showed all tail/claim variants stuck at
// ~200us: 3.2M random 8B global stores are line-transaction-bound (~64
// lines/wave). Here records are physically sorted in LDS first, so the
// copy-out's consecutive threads write consecutive slots of each list
// segment (~10 lines/wave, 5x fewer transactions, byte-bound).
// LDS: rec 100000 + lid 25000 + 3*6252 + scan tmp ~= 144 KB, 1 block/CU.
// Record = int2{ src | (dst&63)<<17 , w_bits }.
// ---------------------------------------------------------------------------
__global__ __launch_bounds__(1024) void bin5_kernel(
    const int* __restrict__ src, const int* __restrict__ dst,
    const float* __restrict__ w, int* __restrict__ gtail,
    int2* __restrict__ lists) {
  __shared__ int2 rec[TILE2];               // 100000 B
  __shared__ unsigned short lid[TILE2];     // 25000 B
  __shared__ int lcnt[NB2];                 // counts, then cursor
  __shared__ int loff[NB2];                 // tile-local exclusive offsets
  __shared__ int lbase[NB2];                // global claimed base
  __shared__ int wsum[16];
  const int t = threadIdx.x;
  const int e0 = blockIdx.x * TILE2;

  for (int i = t; i < NB2; i += 1024) lcnt[i] = 0;
  __syncthreads();

  // pass A: histogram of list id (native int ds_add)
  for (int i = t; i < TILE2; i += 1024)
    atomicAdd(&lcnt[dst[e0 + i] >> 6], 1);   // dst<100000 -> l<=1562
  __syncthreads();

  // block-wide exclusive scan over 1563 counters (2 slots/thread)
  {
    int i0 = 2 * t, i1 = 2 * t + 1;
    int c0 = (i0 < NB2) ? lcnt[i0] : 0;
    int c1 = (i1 < NB2) ? lcnt[i1] : 0;
    int v = c0 + c1;
    int inc = v;
    #pragma unroll
    for (int d = 1; d < 64; d <<= 1) {
      int u = __shfl_up(inc, d, 64);
      if ((t & 63) >= d) inc += u;
    }
    if ((t & 63) == 63) wsum[t >> 6] = inc;
    __syncthreads();
    if (t < 16) {
      int s = wsum[t];
      int inc2 = s;
      #pragma unroll
      for (int d = 1; d < 16; d <<= 1) {
        int u = __shfl_up(inc2, d, 64);
        if (t >= d) inc2 += u;
      }
      wsum[t] = inc2 - s;                    // exclusive wave base
    }
    __syncthreads();
    int excl = (inc - v) + wsum[t >> 6];
    if (i0 < NB2) loff[i0] = excl;
    if (i1 < NB2) loff[i1] = excl + c0;
  }
  __syncthreads();

  // claim global ranges (one atomic per non-empty list), cursor <- loff
  for (int i = t; i < NB2; i += 1024) {
    int c = lcnt[i];
    lbase[i] = (c > 0) ? atomicAdd(&gtail[i], c) : 0;
  }
  __syncthreads();
  for (int i = t; i < NB2; i += 1024) lcnt[i] = loff[i];
  __syncthreads();

  // pass B: re-read slice (L2-hot) and scatter records INTO LDS
  for (int i = t; i < TILE2; i += 1024) {
    int e = e0 + i;
    int d = dst[e];
    int l = d >> 6;
    int p = atomicAdd(&lcnt[l], 1);          // p < TILE2 by construction
    rec[p] = make_int2(src[e] | ((d & 63) << 17), __float_as_int(w[e]));
    lid[p] = (unsigned short)l;
  }
  __syncthreads();

  // copy-out: consecutive q -> consecutive dest within each segment
  for (int q = t; q < TILE2; q += 1024) {
    int l = lid[q];
    int dest = lbase[l] + (q - loff[l]);
    if ((unsigned)dest < (unsigned)LCAP)
      lists[(size_t)l * LCAP + dest] = rec[q];
  }
}

// ---------------------------------------------------------------------------
// K2 (agg v6): one block per 64-dst bucket. LDS counting-sort by composite
// key = row*8 + src_window (512 keys; int atomics only). ROW-major keeps
// each row ONE contiguous segment (mean 32 -> round-8's 8-deep gather
// pipeline intact, unlike round-10's window-major key that shattered
// segments to 4 records and went latency-bound); window-minor makes each
// row's gathers sweep x in ascending-window order (L2 locality).
// Predict: agg4-like 110-125us, FETCH between 166 and 354 MB.
// ---------------------------------------------------------------------------
__global__ __launch_bounds__(256) void agg6_kernel(
    const __half* __restrict__ xh, const int2* __restrict__ lists,
    const int* __restrict__ gtail, float* __restrict__ agg_out,
    float* __restrict__ sw) {
  __shared__ int2 sorted[LCAP];          // 19456 B
  __shared__ int kcnt[NKEY];
  __shared__ int koff[NKEY + 1];
  __shared__ int kcur[NKEY];
  const int b = blockIdx.x;
  const int t = threadIdx.x;
  const int c = min(gtail[b], LCAP);
  const int2* base = lists + (size_t)b * LCAP;

  for (int i = t; i < NKEY; i += 256) kcnt[i] = 0;
  __syncthreads();

  // phase 1: histogram keys (row*8+win; masked -> key<512)
  for (int j = t; j < c; j += 256) {
    int rx = base[j].x;
    int key = ((rx >> 17) & 63) * 8 + ((rx & 0x1FFFF) >> 14);
    atomicAdd(&kcnt[key], 1);
  }
  __syncthreads();

  // wave-0 scan of 512 keys: 8 keys/lane local prefix + shfl scan
  if (t < 64) {
    int base8 = t * 8;
    int loc[8], run = 0;
    #pragma unroll
    for (int i = 0; i < 8; ++i) { loc[i] = run; run += kcnt[base8 + i]; }
    int inc = run;
    #pragma unroll
    for (int d = 1; d < 64; d <<= 1) {
      int u = __shfl_up(inc, d, 64);
      if (t >= d) inc += u;
    }
    int excl = inc - run;
    #pragma unroll
    for (int i = 0; i < 8; ++i) {
      koff[base8 + i] = excl + loc[i];
      kcur[base8 + i] = excl + loc[i];
    }
    if (t == 63) koff[NKEY] = inc;
  }
  __syncthreads();

  // phase 2: counting-sort scatter into LDS (guarded)
  for (int j = t; j < c; j += 256) {
    int2 r = base[j];
    int key = ((r.x >> 17) & 63) * 8 + ((r.x & 0x1FFFF) >> 14);
    int p = atomicAdd(&kcur[key], 1);
    if ((unsigned)p < (unsigned)LCAP) sorted[p] = r;
  }
  __syncthreads();

  // phase 3: per-ROW contiguous segments (all 8 windows), 8 gathers in flight
  const int wv = t >> 6, lane = t & 63;
  const int nd = min(64, N_NODES - b * 64);
  const __half2* xh2 = (const __half2*)xh;
  for (int ri = 0; ri < 16; ++ri) {
    int r = wv * 16 + ri;
    int j0 = min(koff[r * 8], c), j1 = min(koff[r * 8 + 8], c);
    float2 acc = make_float2(0.f, 0.f);
    float sws = 0.f;
    int j = j0;
    for (; j + 8 <= j1; j += 8) {
      int2 e0 = sorted[j];
      int2 e1 = sorted[j + 1];
      int2 e2 = sorted[j + 2];
      int2 e3 = sorted[j + 3];
      int2 e4 = sorted[j + 4];
      int2 e5 = sorted[j + 5];
      int2 e6 = sorted[j + 6];
      int2 e7 = sorted[j + 7];
      float2 v0 = __half22float2(xh2[(size_t)(e0.x & 0x1FFFF) * 64 + lane]);
      float2 v1 = __half22float2(xh2[(size_t)(e1.x & 0x1FFFF) * 64 + lane]);
      float2 v2 = __half22float2(xh2[(size_t)(e2.x & 0x1FFFF) * 64 + lane]);
      float2 v3 = __half22float2(xh2[(size_t)(e3.x & 0x1FFFF) * 64 + lane]);
      float2 v4 = __half22float2(xh2[(size_t)(e4.x & 0x1FFFF) * 64 + lane]);
      float2 v5 = __half22float2(xh2[(size_t)(e5.x & 0x1FFFF) * 64 + lane]);
      float2 v6 = __half22float2(xh2[(size_t)(e6.x & 0x1FFFF) * 64 + lane]);
      float2 v7 = __half22float2(xh2[(size_t)(e7.x & 0x1FFFF) * 64 + lane]);
      float w0 = __int_as_float(e0.y), w1 = __int_as_float(e1.y);
      float w2 = __int_as_float(e2.y), w3 = __int_as_float(e3.y);
      float w4 = __int_as_float(e4.y), w5 = __int_as_float(e5.y);
      float w6 = __int_as_float(e6.y), w7 = __int_as_float(e7.y);
      acc.x = fmaf(w0, v0.x, acc.x); acc.y = fmaf(w0, v0.y, acc.y);
      acc.x = fmaf(w1, v1.x, acc.x); acc.y = fmaf(w1, v1.y, acc.y);
      acc.x = fmaf(w2, v2.x, acc.x); acc.y = fmaf(w2, v2.y, acc.y);
      acc.x = fmaf(w3, v3.x, acc.x); acc.y = fmaf(w3, v3.y, acc.y);
      acc.x = fmaf(w4, v4.x, acc.x); acc.y = fmaf(w4, v4.y, acc.y);
      acc.x = fmaf(w5, v5.x, acc.x); acc.y = fmaf(w5, v5.y, acc.y);
      acc.x = fmaf(w6, v6.x, acc.x); acc.y = fmaf(w6, v6.y, acc.y);
      acc.x = fmaf(w7, v7.x, acc.x); acc.y = fmaf(w7, v7.y, acc.y);
      sws += ((w0 + w1) + (w2 + w3)) + ((w4 + w5) + (w6 + w7));
    }
    for (; j < j1; ++j) {
      int2 e0 = sorted[j];
      float2 v0 = __half22float2(xh2[(size_t)(e0.x & 0x1FFFF) * 64 + lane]);
      float w0 = __int_as_float(e0.y);
      acc.x = fmaf(w0, v0.x, acc.x);
      acc.y = fmaf(w0, v0.y, acc.y);
      sws += w0;
    }
    if (r < nd) {
      ((float2*)agg_out)[(size_t)(b * 64 + r) * 64 + lane] = acc;
      if (lane == 0) sw[b * 64 + r] = sws;
    }
  }
}

// ---------------------------------------------------------------------------
// K3 (linear v3, unchanged): in-place io[r] = io[r]@W^T + sw[r]*b, 64-row
// tiles, Wt-only LDS (2 blocks/CU), broadcast row loads. In-place safe:
// each row read AND written only by the same 16 lanes of one wave.
// ---------------------------------------------------------------------------
__global__ __launch_bounds__(256, 2) void linear3_kernel(
    float* __restrict__ io, const float* __restrict__ W,
    const float* __restrict__ bias, const float* __restrict__ sw) {
  __shared__ float Wt[128][132];   // Wt[k][c] = W[c][k]
  const int t = threadIdx.x;
  const int row0 = blockIdx.x * 64;

  #pragma unroll
  for (int i = 0; i < 16; ++i) {
    int f4 = t + 256 * i;
    int c = f4 >> 5;
    int k = (f4 & 31) * 4;
    float4 v = *(const float4*)(W + (size_t)c * 128 + k);
    Wt[k + 0][c] = v.x;
    Wt[k + 1][c] = v.y;
    Wt[k + 2][c] = v.z;
    Wt[k + 3][c] = v.w;
  }
  __syncthreads();

  const int tx = t & 15;
  const int ty = t >> 4;
  const float* xr[4];
  #pragma unroll
  for (int i = 0; i < 4; ++i) {
    int r = row0 + ty * 4 + i;
    xr[i] = (r < N_NODES) ? (io + (size_t)r * 128) : io;
  }

  float acc[4][8];
  #pragma unroll
  for (int i = 0; i < 4; ++i)
    #pragma unroll
    for (int j = 0; j < 8; ++j) acc[i][j] = 0.f;

  for (int k0 = 0; k0 < 128; k0 += 4) {
    float4 a[4];
    #pragma unroll
    for (int i = 0; i < 4; ++i) a[i] = *(const float4*)(xr[i] + k0);
    #pragma unroll
    for (int kk = 0; kk < 4; ++kk) {
      int k = k0 + kk;
      float4 b0 = *(const float4*)&Wt[k][tx * 8];
      float4 b1 = *(const float4*)&Wt[k][tx * 8 + 4];
      #pragma unroll
      for (int i = 0; i < 4; ++i) {
        float av = (kk == 0) ? a[i].x : (kk == 1) ? a[i].y
                  : (kk == 2) ? a[i].z : a[i].w;
        acc[i][0] = fmaf(av, b0.x, acc[i][0]);
        acc[i][1] = fmaf(av, b0.y, acc[i][1]);
        acc[i][2] = fmaf(av, b0.z, acc[i][2]);
        acc[i][3] = fmaf(av, b0.w, acc[i][3]);
        acc[i][4] = fmaf(av, b1.x, acc[i][4]);
        acc[i][5] = fmaf(av, b1.y, acc[i][5]);
        acc[i][6] = fmaf(av, b1.z, acc[i][6]);
        acc[i][7] = fmaf(av, b1.w, acc[i][7]);
      }
    }
  }

  float4 bb0 = *(const float4*)(bias + tx * 8);
  float4 bb1 = *(const float4*)(bias + tx * 8 + 4);
  #pragma unroll
  for (int i = 0; i < 4; ++i) {
    int r = row0 + ty * 4 + i;
    if (r < N_NODES) {
      float s = sw[r];
      float4 o0 = make_float4(acc[i][0] + s * bb0.x, acc[i][1] + s * bb0.y,
                              acc[i][2] + s * bb0.z, acc[i][3] + s * bb0.w);
      float4 o1 = make_float4(acc[i][4] + s * bb1.x, acc[i][5] + s * bb1.y,
                              acc[i][6] + s * bb1.z, acc[i][7] + s * bb1.w);
      float* orow = io + (size_t)r * 128 + tx * 8;
      *(float4*)orow = o0;
      *(float4*)(orow + 4) = o1;
    }
  }
}

// ---------------------------------------------------------------------------
extern "C" void kernel_launch(void* const* d_in, const int* in_sizes, int n_in,
                              void* d_out, int out_size, void* d_ws, size_t ws_size,
                              hipStream_t stream) {
  const float* x = (const float*)d_in[0];
  const float* w = (const float*)d_in[1];
  const float* W = (const float*)d_in[2];
  const float* bias = (const float*)d_in[3];
  const int* src = (const int*)d_in[4];
  const int* dst = (const int*)d_in[5];
  float* out = (float*)d_out;

  // workspace: xh 25.6MB | lists 30.4MB | gtail 6.3KB | sw 400KB (~56.5MB)
  char* p = (char*)d_ws;
  __half* xh = (__half*)p;
  size_t o = (size_t)N_NODES * 128 * sizeof(__half);
  o = (o + 255) & ~(size_t)255;
  int2* lists = (int2*)(p + o);
  o += (size_t)NB2 * LCAP * sizeof(int2);
  int* gtail = (int*)(p + o);
  o += (size_t)NB2 * sizeof(int);
  o = (o + 255) & ~(size_t)255;
  float* sw = (float*)(p + o);

  hipMemsetAsync(gtail, 0, (size_t)NB2 * sizeof(int), stream);
  cvt_kernel<<<2048, 256, 0, stream>>>(x, xh);
  bin5_kernel<<<NTILE2, 1024, 0, stream>>>(src, dst, w, gtail, lists);
  agg6_kernel<<<NB2, 256, 0, stream>>>(xh, lists, gtail, out, sw);
  linear3_kernel<<<NB2, 256, 0, stream>>>(out, W, bias, sw);
}